// Round 3
// baseline (661.925 us; speedup 1.0000x reference)
//
#include <hip/hip_runtime.h>
#include <math.h>

#define N_PTS 8192
#define B_SZ 4
#define SEED_NUM 409
#define FPS_THREADS 512
#define PPT 16  // points per thread
#define KMAX 196

// Exact IEEE f32 squared distance, same op order as the reference:
// ((dx*dx + dy*dy) + dz*dz), no FMA contraction.
__device__ __forceinline__ float sqdist(float ax, float ay, float az,
                                        float bx, float by, float bz) {
  float dx = __fsub_rn(ax, bx);
  float dy = __fsub_rn(ay, by);
  float dz = __fsub_rn(az, bz);
  return __fadd_rn(__fadd_rn(__fmul_rn(dx, dx), __fmul_rn(dy, dy)),
                   __fmul_rn(dz, dz));
}

typedef float f16v __attribute__((ext_vector_type(16)));

// ---------------------------------------------------------------------------
// Kernel 1: farthest point sampling. One block per batch (4 blocks).
// Point coords + running min-d2 live in ext_vector_type(16) SSA values with
// ONLY compile-time-constant subscripts (macro-expanded): SROA runs before
// loop unrolling, so loop-variable-indexed private arrays fall to scratch
// (round 2: VGPR=52, FETCH_SIZE=208MB of spill reloads). ext-vectors never
// become allocas.
// Argmax reduce: packed u64 key (f32 bits << 32 | (8191 - idx)); values >= 0
// so float bits are monotone; u64 max == (max value, min index) == jnp.argmax.
// One barrier per step (double-buffered partials); winner coords via
// same-address broadcast global load (L1/L2 resident).
// ---------------------------------------------------------------------------
__global__ __launch_bounds__(FPS_THREADS, 1) void fps_kernel(
    const float* __restrict__ pcs, float* __restrict__ seeds) {
  const int b = blockIdx.x;
  const int tid = threadIdx.x;
  const int lane = tid & 63, wid = tid >> 6;  // 8 waves
  const float* base = pcs + (size_t)b * N_PTS * 3;

  f16v px, py, pz, md;
#define FPS_INIT(k)                             \
  {                                             \
    const int i = tid + (k)*FPS_THREADS;        \
    px[k] = base[i * 3 + 0];                    \
    py[k] = base[i * 3 + 1];                    \
    pz[k] = base[i * 3 + 2];                    \
    md[k] = 1e10f; /* ref 1e10 -> f32 exact */  \
  }
  FPS_INIT(0)  FPS_INIT(1)  FPS_INIT(2)  FPS_INIT(3)
  FPS_INIT(4)  FPS_INIT(5)  FPS_INIT(6)  FPS_INIT(7)
  FPS_INIT(8)  FPS_INIT(9)  FPS_INIT(10) FPS_INIT(11)
  FPS_INIT(12) FPS_INIT(13) FPS_INIT(14) FPS_INIT(15)
#undef FPS_INIT

  __shared__ unsigned long long red[2][8];

  // initial point: index 0 (broadcast global read)
  float cx = base[0], cy = base[1], cz = base[2];

  for (int s = 0; s < SEED_NUM; ++s) {
    if (tid == 0) {
      float* sp = seeds + ((size_t)b * SEED_NUM + s) * 3;
      sp[0] = cx; sp[1] = cy; sp[2] = cz;
    }
    float bv = -1.0f;
    int bi = 0;
    // i = tid + k*512: index increases with k, so strict '>' keeps the
    // first (smallest) index on ties within a thread.
#define FPS_UPD(k)                                            \
  {                                                           \
    const float d2 = sqdist(px[k], py[k], pz[k], cx, cy, cz); \
    const float m = fminf(md[k], d2);                         \
    md[k] = m;                                                \
    if (m > bv) { bv = m; bi = tid + (k)*FPS_THREADS; }       \
  }
    FPS_UPD(0)  FPS_UPD(1)  FPS_UPD(2)  FPS_UPD(3)
    FPS_UPD(4)  FPS_UPD(5)  FPS_UPD(6)  FPS_UPD(7)
    FPS_UPD(8)  FPS_UPD(9)  FPS_UPD(10) FPS_UPD(11)
    FPS_UPD(12) FPS_UPD(13) FPS_UPD(14) FPS_UPD(15)
#undef FPS_UPD
    unsigned long long key =
        ((unsigned long long)__float_as_uint(bv) << 32) |
        (unsigned long long)(unsigned)(N_PTS - 1 - bi);
#pragma unroll
    for (int off = 32; off > 0; off >>= 1) {
      const unsigned long long o = __shfl_down(key, off);
      key = (o > key) ? o : key;
    }
    if (lane == 0) red[s & 1][wid] = key;
    __syncthreads();
    unsigned long long kmax = red[s & 1][0];
#pragma unroll
    for (int w = 1; w < 8; ++w) {
      const unsigned long long o = red[s & 1][w];
      kmax = (o > kmax) ? o : kmax;
    }
    const int ci = N_PTS - 1 - (int)(unsigned)(kmax & 0xffffffffull);
    const float* cp = base + (size_t)ci * 3;
    cx = cp[0]; cy = cp[1]; cz = cp[2];
  }
}

// ---------------------------------------------------------------------------
// Kernel 2: per (group, percentage): ball query (first K valid in index
// order via ballot prefix-sum compaction into LDS) + count, then 2nd-NN
// within the group, clutter sum and imbalance/gnum accumulated via double
// atomics. (unchanged — passed with absmax 0.0)
// ---------------------------------------------------------------------------
__global__ __launch_bounds__(256) void group_kernel(
    const float* __restrict__ pcs, const float* __restrict__ seeds,
    double* __restrict__ totS /*[5]*/, double* __restrict__ accA /*[5][4]*/) {
  const int g = blockIdx.x;  // 0 .. B*SEED_NUM-1
  const int p = blockIdx.y;  // 0 .. 4
  const int b = g / SEED_NUM;
  const int tid = threadIdx.x;
  const int lane = tid & 63, wid = tid >> 6;

  const double P[5] = {0.004, 0.006, 0.008, 0.01, 0.012};
  const double pd = P[p];
  const double rd = sqrt(pd);
  const float r2 = (float)(rd * rd);          // weak f32 cast of python r*r
  const double expn_d = 8192.0 * pd;          // exp_num (f64)
  const int K = (int)(2.0 * expn_d);          // 65, 98, 131, 163, 196
  const float expn_f = (float)expn_d;
  const float expect_dis = sqrtf((float)(M_PI / expn_d * pd));  // = sqrt(pi/N)

  const float* base = pcs + (size_t)b * N_PTS * 3;
  const float* sp = seeds + (size_t)g * 3;
  const float sx = sp[0], sy = sp[1], sz = sp[2];

  __shared__ float gx[KMAX], gy[KMAX], gz[KMAX];
  __shared__ int wtot[4];
  __shared__ double wsum[4];

  int run = 0;  // running valid count (uniform across block)
  for (int base_i = 0; base_i < N_PTS; base_i += 256) {
    const int i = base_i + tid;
    const float x = base[i * 3 + 0];
    const float y = base[i * 3 + 1];
    const float z = base[i * 3 + 2];
    const float d2 = sqdist(x, y, z, sx, sy, sz);
    const bool valid = d2 < r2;
    const unsigned long long m = __ballot(valid);
    if (lane == 0) wtot[wid] = __popcll(m);
    __syncthreads();
    int pos = run + __popcll(m & ((1ull << lane) - 1ull));
    for (int w = 0; w < wid; ++w) pos += wtot[w];
    if (valid && pos < K) { gx[pos] = x; gy[pos] = y; gz[pos] = z; }
    run += wtot[0] + wtot[1] + wtot[2] + wtot[3];
    __syncthreads();  // protect wtot (and gx writes) before next chunk
  }
  const int gnum = run < K ? run : K;  // = min(cnt, K), >= 1 (seed is in pcs)

  // 2nd-smallest pairwise d2 per row (self-distance 0 included => nearest
  // neighbor). Exact-tie handling matches top_k-by-value.
  double localS = 0.0;
  if (tid < gnum) {
    const float xi = gx[tid], yi = gy[tid], zi = gz[tid];
    float m1 = INFINITY, m2 = INFINITY;
    for (int j = 0; j < gnum; ++j) {
      const float d2 = sqdist(xi, yi, zi, gx[j], gy[j], gz[j]);
      if (d2 < m1) { m2 = m1; m1 = d2; }
      else if (d2 < m2) { m2 = d2; }
    }
    const float nn2 = (m2 > 1e37f) ? 0.0f : m2;  // inf (gnum==1) -> 0
    const float nnd = (nn2 > 0.0f) ? sqrtf(nn2) : 0.0f;
    const float diff = __fsub_rn(nnd, expect_dis);
    const float clut = __fdiv_rn(__fmul_rn(diff, diff),
                                 __fadd_rn(expect_dis, 1e-12f));
    localS = (double)clut;
  }
#pragma unroll
  for (int off = 32; off > 0; off >>= 1) localS += __shfl_down(localS, off);
  if (lane == 0) wsum[wid] = localS;
  __syncthreads();
  if (tid == 0) {
    const double S = wsum[0] + wsum[1] + wsum[2] + wsum[3];
    atomicAdd(&totS[p], S);
    const float gf = (float)gnum;
    const float d = __fsub_rn(gf, expn_f);
    const float imb = __fdiv_rn(__fmul_rn(d, d), expn_f);
    atomicAdd(&accA[p * 4 + b], (double)imb / (double)gf);
  }
}

// ---------------------------------------------------------------------------
// Kernel 3: loss[b] = (1/5) * sum_p totS[p] * (accA[p][b] / 409)
// ---------------------------------------------------------------------------
__global__ void finalize_kernel(const double* __restrict__ totS,
                                const double* __restrict__ accA,
                                float* __restrict__ out) {
  const int b = threadIdx.x;
  if (b < B_SZ) {
    double acc = 0.0;
    for (int p = 0; p < 5; ++p)
      acc += totS[p] * (accA[p * 4 + b] / (double)SEED_NUM);
    out[b] = (float)(acc / 5.0);
  }
}

__global__ void zero_kernel(double* __restrict__ ptr) {
  const int t = threadIdx.x;
  if (t < 25) ptr[t] = 0.0;  // totS[5] + accA[20]
}

extern "C" void kernel_launch(void* const* d_in, const int* in_sizes, int n_in,
                              void* d_out, int out_size, void* d_ws,
                              size_t ws_size, hipStream_t stream) {
  (void)in_sizes; (void)n_in; (void)out_size; (void)ws_size;
  const float* pcs = (const float*)d_in[0];
  float* out = (float*)d_out;

  // ws layout: seeds (B*409*3 f32 = 19632 B, 8-aligned), then 25 doubles.
  float* seeds = (float*)d_ws;
  double* sums = (double*)((char*)d_ws + 19632);

  zero_kernel<<<1, 32, 0, stream>>>(sums);
  fps_kernel<<<B_SZ, FPS_THREADS, 0, stream>>>(pcs, seeds);
  dim3 grid(B_SZ * SEED_NUM, 5);
  group_kernel<<<grid, 256, 0, stream>>>(pcs, seeds, sums, sums + 5);
  finalize_kernel<<<1, 64, 0, stream>>>(sums, sums + 5, out);
}

// Round 4
// 649.915 us; speedup vs baseline: 1.0185x; 1.0185x over previous
//
#include <hip/hip_runtime.h>
#include <math.h>

#define N_PTS 8192
#define B_SZ 4
#define SEED_NUM 409
#define FPS_THREADS 512
#define KMAX 196

// Exact IEEE f32 squared distance, same op order as the reference:
// ((dx*dx + dy*dy) + dz*dz), no FMA contraction.
__device__ __forceinline__ float sqdist(float ax, float ay, float az,
                                        float bx, float by, float bz) {
  float dx = __fsub_rn(ax, bx);
  float dy = __fsub_rn(ay, by);
  float dz = __fsub_rn(az, bz);
  return __fadd_rn(__fadd_rn(__fmul_rn(dx, dx), __fmul_rn(dy, dy)),
                   __fmul_rn(dz, dz));
}

#define FOR16(M) \
  M(0) M(1) M(2) M(3) M(4) M(5) M(6) M(7) \
  M(8) M(9) M(10) M(11) M(12) M(13) M(14) M(15)

// ---------------------------------------------------------------------------
// Kernel 1: farthest point sampling. One block per batch (4 blocks).
// R2/R3 forensics: VGPR=52 + FETCH=208MB with NO write traffic means the
// allocator kept only md[] and REMATERIALIZED px/py/pz by re-loading from
// global every step (invariant loads from a const __restrict__ pointer are
// remat-eligible) -> ~2810 cyc/step of serial load latency. Fix: pass each
// coordinate through an empty asm "+v" after the init load. An asm result is
// opaque (not a load), so it cannot be rematerialized -- it must stay live
// in a VGPR. Points are also staged to LDS once so the per-step winner-coord
// broadcast is a ~120cyc same-address LDS read, not a dependent global load.
// Argmax reduce: packed u64 key (f32 bits << 32 | (8191 - idx)); values >= 0
// so float bits are monotone; u64 max == (max value, min index) == jnp.argmax.
// One barrier per step (double-buffered partials).
// ---------------------------------------------------------------------------
__global__ __launch_bounds__(FPS_THREADS, 1) void fps_kernel(
    const float* __restrict__ pcs, float* __restrict__ seeds) {
  const int b = blockIdx.x;
  const int tid = threadIdx.x;
  const int lane = tid & 63, wid = tid >> 6;  // 8 waves
  const float* base = pcs + (size_t)b * N_PTS * 3;

  __shared__ float spts[N_PTS * 3];  // 96 KiB: winner-coord broadcast source
  __shared__ unsigned long long red[2][8];

#define FPS_DECL(k) float px##k, py##k, pz##k, md##k;
  FOR16(FPS_DECL)
#undef FPS_DECL

#define FPS_INIT(k)                              \
  {                                              \
    const int i = tid + (k)*FPS_THREADS;         \
    px##k = base[i * 3 + 0];                     \
    py##k = base[i * 3 + 1];                     \
    pz##k = base[i * 3 + 2];                     \
    md##k = 1e10f; /* ref 1e10 -> f32 exact */   \
    spts[i * 3 + 0] = px##k;                     \
    spts[i * 3 + 1] = py##k;                     \
    spts[i * 3 + 2] = pz##k;                     \
  }
  FOR16(FPS_INIT)
#undef FPS_INIT

  // Pin the 48 coordinate values in VGPRs: asm results cannot be
  // rematerialized from memory by the register allocator.
#define FPS_PIN(k) asm volatile("" : "+v"(px##k), "+v"(py##k), "+v"(pz##k));
  FOR16(FPS_PIN)
#undef FPS_PIN

  // initial point: index 0 (broadcast global read)
  float cx = base[0], cy = base[1], cz = base[2];

  for (int s = 0; s < SEED_NUM; ++s) {
    if (tid == 0) {
      float* sp = seeds + ((size_t)b * SEED_NUM + s) * 3;
      sp[0] = cx; sp[1] = cy; sp[2] = cz;
    }
    float bv = -1.0f;
    int bi = 0;
    // i = tid + k*512: index increases with k, so strict '>' keeps the
    // first (smallest) index on ties within a thread.
#define FPS_UPD(k)                                                  \
  {                                                                 \
    const float d2 = sqdist(px##k, py##k, pz##k, cx, cy, cz);       \
    const float m = fminf(md##k, d2);                               \
    md##k = m;                                                      \
    if (m > bv) { bv = m; bi = tid + (k)*FPS_THREADS; }             \
  }
    FOR16(FPS_UPD)
#undef FPS_UPD
    unsigned long long key =
        ((unsigned long long)__float_as_uint(bv) << 32) |
        (unsigned long long)(unsigned)(N_PTS - 1 - bi);
#pragma unroll
    for (int off = 32; off > 0; off >>= 1) {
      const unsigned long long o = __shfl_down(key, off);
      key = (o > key) ? o : key;
    }
    if (lane == 0) red[s & 1][wid] = key;
    __syncthreads();
    unsigned long long kmax = red[s & 1][0];
#pragma unroll
    for (int w = 1; w < 8; ++w) {
      const unsigned long long o = red[s & 1][w];
      kmax = (o > kmax) ? o : kmax;
    }
    const int ci = N_PTS - 1 - (int)(unsigned)(kmax & 0xffffffffull);
    // same-address LDS broadcast (points staged at init; the in-loop
    // barrier above already ordered staging before the first read)
    cx = spts[ci * 3 + 0];
    cy = spts[ci * 3 + 1];
    cz = spts[ci * 3 + 2];
  }
}

// ---------------------------------------------------------------------------
// Kernel 2: per (group, percentage): ball query (first K valid in index
// order via ballot prefix-sum compaction into LDS) + count, then 2nd-NN
// within the group, clutter sum and imbalance/gnum accumulated via double
// atomics. (unchanged — passed with absmax 0.0)
// ---------------------------------------------------------------------------
__global__ __launch_bounds__(256) void group_kernel(
    const float* __restrict__ pcs, const float* __restrict__ seeds,
    double* __restrict__ totS /*[5]*/, double* __restrict__ accA /*[5][4]*/) {
  const int g = blockIdx.x;  // 0 .. B*SEED_NUM-1
  const int p = blockIdx.y;  // 0 .. 4
  const int b = g / SEED_NUM;
  const int tid = threadIdx.x;
  const int lane = tid & 63, wid = tid >> 6;

  const double P[5] = {0.004, 0.006, 0.008, 0.01, 0.012};
  const double pd = P[p];
  const double rd = sqrt(pd);
  const float r2 = (float)(rd * rd);          // weak f32 cast of python r*r
  const double expn_d = 8192.0 * pd;          // exp_num (f64)
  const int K = (int)(2.0 * expn_d);          // 65, 98, 131, 163, 196
  const float expn_f = (float)expn_d;
  const float expect_dis = sqrtf((float)(M_PI / expn_d * pd));  // = sqrt(pi/N)

  const float* base = pcs + (size_t)b * N_PTS * 3;
  const float* sp = seeds + (size_t)g * 3;
  const float sx = sp[0], sy = sp[1], sz = sp[2];

  __shared__ float gx[KMAX], gy[KMAX], gz[KMAX];
  __shared__ int wtot[4];
  __shared__ double wsum[4];

  int run = 0;  // running valid count (uniform across block)
  for (int base_i = 0; base_i < N_PTS; base_i += 256) {
    const int i = base_i + tid;
    const float x = base[i * 3 + 0];
    const float y = base[i * 3 + 1];
    const float z = base[i * 3 + 2];
    const float d2 = sqdist(x, y, z, sx, sy, sz);
    const bool valid = d2 < r2;
    const unsigned long long m = __ballot(valid);
    if (lane == 0) wtot[wid] = __popcll(m);
    __syncthreads();
    int pos = run + __popcll(m & ((1ull << lane) - 1ull));
    for (int w = 0; w < wid; ++w) pos += wtot[w];
    if (valid && pos < K) { gx[pos] = x; gy[pos] = y; gz[pos] = z; }
    run += wtot[0] + wtot[1] + wtot[2] + wtot[3];
    __syncthreads();  // protect wtot (and gx writes) before next chunk
  }
  const int gnum = run < K ? run : K;  // = min(cnt, K), >= 1 (seed is in pcs)

  // 2nd-smallest pairwise d2 per row (self-distance 0 included => nearest
  // neighbor). Exact-tie handling matches top_k-by-value.
  double localS = 0.0;
  if (tid < gnum) {
    const float xi = gx[tid], yi = gy[tid], zi = gz[tid];
    float m1 = INFINITY, m2 = INFINITY;
    for (int j = 0; j < gnum; ++j) {
      const float d2 = sqdist(xi, yi, zi, gx[j], gy[j], gz[j]);
      if (d2 < m1) { m2 = m1; m1 = d2; }
      else if (d2 < m2) { m2 = d2; }
    }
    const float nn2 = (m2 > 1e37f) ? 0.0f : m2;  // inf (gnum==1) -> 0
    const float nnd = (nn2 > 0.0f) ? sqrtf(nn2) : 0.0f;
    const float diff = __fsub_rn(nnd, expect_dis);
    const float clut = __fdiv_rn(__fmul_rn(diff, diff),
                                 __fadd_rn(expect_dis, 1e-12f));
    localS = (double)clut;
  }
#pragma unroll
  for (int off = 32; off > 0; off >>= 1) localS += __shfl_down(localS, off);
  if (lane == 0) wsum[wid] = localS;
  __syncthreads();
  if (tid == 0) {
    const double S = wsum[0] + wsum[1] + wsum[2] + wsum[3];
    atomicAdd(&totS[p], S);
    const float gf = (float)gnum;
    const float d = __fsub_rn(gf, expn_f);
    const float imb = __fdiv_rn(__fmul_rn(d, d), expn_f);
    atomicAdd(&accA[p * 4 + b], (double)imb / (double)gf);
  }
}

// ---------------------------------------------------------------------------
// Kernel 3: loss[b] = (1/5) * sum_p totS[p] * (accA[p][b] / 409)
// ---------------------------------------------------------------------------
__global__ void finalize_kernel(const double* __restrict__ totS,
                                const double* __restrict__ accA,
                                float* __restrict__ out) {
  const int b = threadIdx.x;
  if (b < B_SZ) {
    double acc = 0.0;
    for (int p = 0; p < 5; ++p)
      acc += totS[p] * (accA[p * 4 + b] / (double)SEED_NUM);
    out[b] = (float)(acc / 5.0);
  }
}

__global__ void zero_kernel(double* __restrict__ ptr) {
  const int t = threadIdx.x;
  if (t < 25) ptr[t] = 0.0;  // totS[5] + accA[20]
}

extern "C" void kernel_launch(void* const* d_in, const int* in_sizes, int n_in,
                              void* d_out, int out_size, void* d_ws,
                              size_t ws_size, hipStream_t stream) {
  (void)in_sizes; (void)n_in; (void)out_size; (void)ws_size;
  const float* pcs = (const float*)d_in[0];
  float* out = (float*)d_out;

  // ws layout: seeds (B*409*3 f32 = 19632 B, 8-aligned), then 25 doubles.
  float* seeds = (float*)d_ws;
  double* sums = (double*)((char*)d_ws + 19632);

  zero_kernel<<<1, 32, 0, stream>>>(sums);
  fps_kernel<<<B_SZ, FPS_THREADS, 0, stream>>>(pcs, seeds);
  dim3 grid(B_SZ * SEED_NUM, 5);
  group_kernel<<<grid, 256, 0, stream>>>(pcs, seeds, sums, sums + 5);
  finalize_kernel<<<1, 64, 0, stream>>>(sums, sums + 5, out);
}

// Round 5
// 623.341 us; speedup vs baseline: 1.0619x; 1.0426x over previous
//
#include <hip/hip_runtime.h>
#include <math.h>

#define N_PTS 8192
#define B_SZ 4
#define SEED_NUM 409
#define FPS_THREADS 512
#define LTOT 653  // 65+98+131+163+196

// Exact IEEE f32 squared distance, same op order as the reference:
// ((dx*dx + dy*dy) + dz*dz), no FMA contraction.
__device__ __forceinline__ float sqdist(float ax, float ay, float az,
                                        float bx, float by, float bz) {
  float dx = __fsub_rn(ax, bx);
  float dy = __fsub_rn(ay, by);
  float dz = __fsub_rn(az, bz);
  return __fadd_rn(__fadd_rn(__fmul_rn(dx, dx), __fmul_rn(dy, dy)),
                   __fmul_rn(dz, dz));
}

#define FOR16(M) \
  M(0) M(1) M(2) M(3) M(4) M(5) M(6) M(7) \
  M(8) M(9) M(10) M(11) M(12) M(13) M(14) M(15)

// ---------------------------------------------------------------------------
// Kernel 1: farthest point sampling (unchanged from round 4).
// NOTE (journal): FETCH_SIZE is KB, not MB — fps was never fetch-bound; it is
// latency-bound on the serial step chain (~2730 cyc/step vs ~830 VALU floor).
// ---------------------------------------------------------------------------
__global__ __launch_bounds__(FPS_THREADS, 1) void fps_kernel(
    const float* __restrict__ pcs, float* __restrict__ seeds) {
  const int b = blockIdx.x;
  const int tid = threadIdx.x;
  const int lane = tid & 63, wid = tid >> 6;  // 8 waves
  const float* base = pcs + (size_t)b * N_PTS * 3;

  __shared__ float spts[N_PTS * 3];  // 96 KiB: winner-coord broadcast source
  __shared__ unsigned long long red[2][8];

#define FPS_DECL(k) float px##k, py##k, pz##k, md##k;
  FOR16(FPS_DECL)
#undef FPS_DECL

#define FPS_INIT(k)                              \
  {                                              \
    const int i = tid + (k)*FPS_THREADS;         \
    px##k = base[i * 3 + 0];                     \
    py##k = base[i * 3 + 1];                     \
    pz##k = base[i * 3 + 2];                     \
    md##k = 1e10f; /* ref 1e10 -> f32 exact */   \
    spts[i * 3 + 0] = px##k;                     \
    spts[i * 3 + 1] = py##k;                     \
    spts[i * 3 + 2] = pz##k;                     \
  }
  FOR16(FPS_INIT)
#undef FPS_INIT

  // Pin coords in VGPRs (asm results can't be rematerialized from memory).
#define FPS_PIN(k) asm volatile("" : "+v"(px##k), "+v"(py##k), "+v"(pz##k));
  FOR16(FPS_PIN)
#undef FPS_PIN

  float cx = base[0], cy = base[1], cz = base[2];

  for (int s = 0; s < SEED_NUM; ++s) {
    if (tid == 0) {
      float* sp = seeds + ((size_t)b * SEED_NUM + s) * 3;
      sp[0] = cx; sp[1] = cy; sp[2] = cz;
    }
    float bv = -1.0f;
    int bi = 0;
    // i = tid + k*512: index increases with k, so strict '>' keeps the
    // first (smallest) index on ties within a thread.
#define FPS_UPD(k)                                                  \
  {                                                                 \
    const float d2 = sqdist(px##k, py##k, pz##k, cx, cy, cz);       \
    const float m = fminf(md##k, d2);                               \
    md##k = m;                                                      \
    if (m > bv) { bv = m; bi = tid + (k)*FPS_THREADS; }             \
  }
    FOR16(FPS_UPD)
#undef FPS_UPD
    unsigned long long key =
        ((unsigned long long)__float_as_uint(bv) << 32) |
        (unsigned long long)(unsigned)(N_PTS - 1 - bi);
#pragma unroll
    for (int off = 32; off > 0; off >>= 1) {
      const unsigned long long o = __shfl_down(key, off);
      key = (o > key) ? o : key;
    }
    if (lane == 0) red[s & 1][wid] = key;
    __syncthreads();
    unsigned long long kmax = red[s & 1][0];
#pragma unroll
    for (int w = 1; w < 8; ++w) {
      const unsigned long long o = red[s & 1][w];
      kmax = (o > kmax) ? o : kmax;
    }
    const int ci = N_PTS - 1 - (int)(unsigned)(kmax & 0xffffffffull);
    cx = spts[ci * 3 + 0];
    cy = spts[ci * 3 + 1];
    cz = spts[ci * 3 + 2];
  }
}

// ---------------------------------------------------------------------------
// Kernel 2 (REWRITTEN): one block per group, ALL 5 percentages at once.
// Key facts: (a) valid-sets nest (r grows with p) -> one d2 per point serves
// all 5 membership tests; (b) the per-member 2nd-NN / clutter sum depends
// only on the member SET, not its order -> when cnt<=K we can collect members
// with order-free LDS atomic appends (no per-chunk barriers, no ballot
// compaction). If cnt>K (prob ~1e-30 for these uniform inputs; mean counts
// 9..45 vs caps 65..196) the set must be the K smallest indices -> rare
// block-uniform ordered-recompaction fallback preserves exactness.
// KNN: 4 threads per row, two-min merged via shfl_xor (multiset two-min is
// partition-invariant -> bitwise-identical nn2).
// ---------------------------------------------------------------------------
__global__ __launch_bounds__(256) void group_kernel(
    const float* __restrict__ pcs, const float* __restrict__ seeds,
    double* __restrict__ totS /*[5]*/, double* __restrict__ accA /*[5][4]*/) {
  const int g = blockIdx.x;  // 0 .. B*SEED_NUM-1
  const int b = g / SEED_NUM;
  const int tid = threadIdx.x;
  const int lane = tid & 63, wid = tid >> 6;

  const int Kc[5] = {65, 98, 131, 163, 196};
  const int off[5] = {0, 65, 163, 294, 457};
  const double Pd[5] = {0.004, 0.006, 0.008, 0.01, 0.012};
  float r2c[5], expnf[5], expdc[5];
#pragma unroll
  for (int p = 0; p < 5; ++p) {
    const double pd = Pd[p];
    const double rd = sqrt(pd);
    r2c[p] = (float)(rd * rd);                     // weak f32 cast of r*r
    const double expn_d = 8192.0 * pd;
    expnf[p] = (float)expn_d;
    expdc[p] = sqrtf((float)(M_PI / expn_d * pd));  // expect_dis (= sqrt(pi/N))
  }

  const float* base = pcs + (size_t)b * N_PTS * 3;
  const float* sp = seeds + (size_t)g * 3;
  const float sx = sp[0], sy = sp[1], sz = sp[2];

  __shared__ float lx[LTOT], ly[LTOT], lz[LTOT];
  __shared__ int cnt[5];
  __shared__ int wtot[4];     // fallback path only
  __shared__ double wsum[4];

  if (tid < 5) cnt[tid] = 0;
  __syncthreads();

  // ---- single barrier-free scan: d2 once, append to each nested list ----
  const float r2max = r2c[4];
  for (int i = tid; i < N_PTS; i += 256) {
    const float x = base[i * 3 + 0];
    const float y = base[i * 3 + 1];
    const float z = base[i * 3 + 2];
    const float d2 = sqdist(x, y, z, sx, sy, sz);
    if (d2 < r2max) {
#pragma unroll
      for (int p = 0; p < 5; ++p) {
        if (d2 < r2c[p]) {
          const int pos = atomicAdd(&cnt[p], 1);
          if (pos < Kc[p]) {
            lx[off[p] + pos] = x;
            ly[off[p] + pos] = y;
            lz[off[p] + pos] = z;
          }
        }
      }
    }
  }
  __syncthreads();

  // ---- rare fallback: cnt>K needs the K smallest indices (ordered) ----
#pragma unroll
  for (int p = 0; p < 5; ++p) {
    if (cnt[p] > Kc[p]) {  // block-uniform (LDS value, post-barrier)
      int run = 0;
      for (int base_i = 0; base_i < N_PTS; base_i += 256) {
        const int i = base_i + tid;
        const float x = base[i * 3 + 0];
        const float y = base[i * 3 + 1];
        const float z = base[i * 3 + 2];
        const float d2 = sqdist(x, y, z, sx, sy, sz);
        const bool valid = d2 < r2c[p];
        const unsigned long long m = __ballot(valid);
        if (lane == 0) wtot[wid] = __popcll(m);
        __syncthreads();
        int pos = run + __popcll(m & ((1ull << lane) - 1ull));
        for (int w = 0; w < wid; ++w) pos += wtot[w];
        if (valid && pos < Kc[p]) {
          lx[off[p] + pos] = x; ly[off[p] + pos] = y; lz[off[p] + pos] = z;
        }
        run += wtot[0] + wtot[1] + wtot[2] + wtot[3];
        __syncthreads();
      }
    }
  }

  // ---- KNN + clutter per percentage: 4 threads/row, shfl two-min merge ----
#pragma unroll
  for (int p = 0; p < 5; ++p) {
    const int gn = min(cnt[p], Kc[p]);  // gnum >= 1 (seed itself is in pcs)
    const float ed = expdc[p];
    const int lb = off[p];
    double localS = 0.0;
    for (int r0 = 0; r0 < gn; r0 += 64) {
      const int row = r0 + (tid >> 2);
      const int sub = tid & 3;
      float m1 = INFINITY, m2 = INFINITY;
      if (row < gn) {
        const float xi = lx[lb + row], yi = ly[lb + row], zi = lz[lb + row];
        for (int j = sub; j < gn; j += 4) {
          const float d2 = sqdist(xi, yi, zi, lx[lb + j], ly[lb + j], lz[lb + j]);
          if (d2 < m1) { m2 = m1; m1 = d2; }
          else if (d2 < m2) { m2 = d2; }
        }
      }
      // merge (m1,m2) pairs across the 4 sub-lanes (multiset two-min)
#pragma unroll
      for (int d = 1; d <= 2; d <<= 1) {
        const float om1 = __shfl_xor(m1, d);
        const float om2 = __shfl_xor(m2, d);
        const float lo = fminf(m1, om1);
        const float hi = fmaxf(m1, om1);
        m2 = fminf(fminf(m2, om2), hi);
        m1 = lo;
      }
      if (row < gn && sub == 0) {
        const float nn2 = (m2 > 1e37f) ? 0.0f : m2;  // inf (gn==1) -> 0
        const float nnd = (nn2 > 0.0f) ? sqrtf(nn2) : 0.0f;
        const float diff = __fsub_rn(nnd, ed);
        const float clut = __fdiv_rn(__fmul_rn(diff, diff),
                                     __fadd_rn(ed, 1e-12f));
        localS += (double)clut;
      }
    }
#pragma unroll
    for (int o = 32; o > 0; o >>= 1) localS += __shfl_down(localS, o);
    if (lane == 0) wsum[wid] = localS;
    __syncthreads();
    if (tid == 0) {
      const double S = wsum[0] + wsum[1] + wsum[2] + wsum[3];
      atomicAdd(&totS[p], S);
      const float gf = (float)gn;
      const float dd = __fsub_rn(gf, expnf[p]);
      const float imb = __fdiv_rn(__fmul_rn(dd, dd), expnf[p]);
      atomicAdd(&accA[p * 4 + b], (double)imb / (double)gf);
    }
    __syncthreads();  // wsum reused next p
  }
}

// ---------------------------------------------------------------------------
// Kernel 3: loss[b] = (1/5) * sum_p totS[p] * (accA[p][b] / 409)
// ---------------------------------------------------------------------------
__global__ void finalize_kernel(const double* __restrict__ totS,
                                const double* __restrict__ accA,
                                float* __restrict__ out) {
  const int b = threadIdx.x;
  if (b < B_SZ) {
    double acc = 0.0;
    for (int p = 0; p < 5; ++p)
      acc += totS[p] * (accA[p * 4 + b] / (double)SEED_NUM);
    out[b] = (float)(acc / 5.0);
  }
}

__global__ void zero_kernel(double* __restrict__ ptr) {
  const int t = threadIdx.x;
  if (t < 25) ptr[t] = 0.0;  // totS[5] + accA[20]
}

extern "C" void kernel_launch(void* const* d_in, const int* in_sizes, int n_in,
                              void* d_out, int out_size, void* d_ws,
                              size_t ws_size, hipStream_t stream) {
  (void)in_sizes; (void)n_in; (void)out_size; (void)ws_size;
  const float* pcs = (const float*)d_in[0];
  float* out = (float*)d_out;

  // ws layout: seeds (B*409*3 f32 = 19632 B, 8-aligned), then 25 doubles.
  float* seeds = (float*)d_ws;
  double* sums = (double*)((char*)d_ws + 19632);

  zero_kernel<<<1, 32, 0, stream>>>(sums);
  fps_kernel<<<B_SZ, FPS_THREADS, 0, stream>>>(pcs, seeds);
  group_kernel<<<B_SZ * SEED_NUM, 256, 0, stream>>>(pcs, seeds, sums, sums + 5);
  finalize_kernel<<<1, 64, 0, stream>>>(sums, sums + 5, out);
}